// Round 3
// baseline (507.203 us; speedup 1.0000x reference)
//
#include <hip/hip_runtime.h>
#include <cstdint>

// Problem constants (fixed shapes)
#define E_DIM   576
#define HEADS   18
#define NPTS    12
#define DDEPTH  5
#define HDIM    32
#define BSZ     2
#define GH      64
#define GW      80
#define NQ      (GH*GW)       // 5120
#define NTOK    (NQ*DDEPTH)   // 25600
#define MIXW    864           // 648 offsets + 216 attn logits
#define BQ_TOT  (BSZ*NQ)      // 10240

typedef __attribute__((ext_vector_type(8))) short short8;
typedef __attribute__((ext_vector_type(4))) float f32x4;
typedef __attribute__((ext_vector_type(4))) uint32_t u32x4;

__device__ __forceinline__ float b2f_lo(uint32_t u) {
    union { uint32_t u; float f; } v; v.u = u << 16; return v.f;
}
__device__ __forceinline__ float b2f_hi(uint32_t u) {
    union { uint32_t u; float f; } v; v.u = u & 0xffff0000u; return v.f;
}
__device__ __forceinline__ ushort f2b(float f) {
    union { float f; uint32_t u; } v; v.f = f;
    return (ushort)((v.u + 0x7fffu + ((v.u >> 16) & 1u)) >> 16);
}
__device__ __forceinline__ uint32_t pkbf(float a, float b) {
    return (uint32_t)f2b(a) | ((uint32_t)f2b(b) << 16);
}

// ---------------------------------------------------------------------------
// all weight prep in one launch
__global__ void prep_weights(const float* __restrict__ W_v, const float* __restrict__ W_out,
                             const float* __restrict__ W_off, const float* __restrict__ W_attn,
                             const float* __restrict__ b_off, const float* __restrict__ b_attn,
                             ushort* __restrict__ wt_v, ushort* __restrict__ wt_out,
                             ushort* __restrict__ wt_mix, float* __restrict__ bias_mix) {
    int idx = blockIdx.x * blockDim.x + threadIdx.x;
    if (idx < 864) bias_mix[idx] = (idx < 648) ? b_off[idx] : b_attn[idx - 648];
    if (idx < 331776) {
        int n = idx / E_DIM, k = idx - n * E_DIM;
        wt_v[idx] = f2b(W_v[(size_t)k * E_DIM + n]);
    } else if (idx < 663552) {
        int j = idx - 331776;
        int n = j / E_DIM, k = j - n * E_DIM;
        wt_out[j] = f2b(W_out[(size_t)k * E_DIM + n]);
    } else if (idx < 1161216) {
        int j = idx - 663552;
        int n = j / E_DIM, k = j - n * E_DIM;
        float v = (n < 648) ? W_off[(size_t)k * 648 + n] : W_attn[(size_t)k * 216 + (n - 648)];
        wt_mix[j] = f2b(v);
    }
}

// ---------------------------------------------------------------------------
// MFMA GEMM: C[M,N] = A[M,K] @ Bt[N,K]^T + bias[N]
// Tile 128x96, BK=32, 256 threads = 4 waves in a 2x2 grid (each wave 64x48).
//
// A-operand modes (fused fp32->bf16 cast in the staging path):
//   AM_BF16  : A already bf16 in HBM, staged via global_load_lds (round-2 path)
//   AM_F32   : A fp32 in HBM; reg-staged (4x dwordx4 -> f2b pack -> 2x ds_write_b128)
//   AM_F32ADD: two fp32 streams summed then packed (query + query_pos)
// The conversion VALU work runs in the MFMA shadow (VALU was 79% idle).
//
// LDS layout: 16-row chunks of [16][BK] ushorts (1024 B). Within a chunk the
// 4 16-B k-slots of row r are XOR-swizzled: phys_slot = logical_slot ^ ((r>>1)&3).
// Read side verified round 1: SQ_LDS_BANK_CONFLICT 5.53M -> 0.
// Write side (reg-staged): lane l of wave w owns row ((w&1)<<6)|l, khalf=w>>1;
// per 16-lane phase the bank-bases 16*(l&1)+4*phys cover all 8 4-bank groups
// with 2 lanes each = conflict-free.
//
// Grid is (N/TN, M/TM): x (N) varies fastest so consecutive blocks share one
// A-panel -> A-panel L2/L3 reuse.
#define TM 128
#define TN 96
#define BK 32

#define AM_BF16   0
#define AM_F32    1
#define AM_F32ADD 2

__device__ __forceinline__ void async_cp16(const ushort* gsrc, ushort* ldst) {
    __builtin_amdgcn_global_load_lds(
        (const __attribute__((address_space(1))) void*)gsrc,
        (__attribute__((address_space(3))) void*)ldst, 16, 0, 0);
}

template <int AMODE, typename OutT>
__global__ void gemm_mfma(const void* __restrict__ Apv, const float* __restrict__ A2,
                          const ushort* __restrict__ Bt,
                          const float* __restrict__ bias, OutT* __restrict__ C,
                          int M, int N, int K, int ldc) {
    __shared__ __align__(16) ushort Asb[2][TM * BK];   // 8 chunks [16][32], swizzled slots
    __shared__ __align__(16) ushort Bsb[2][TN * BK];   // 6 chunks [16][32], swizzled slots
    const int tid  = threadIdx.x;
    const int wave = tid >> 6;
    const int lane = tid & 63;
    const int m16  = lane & 15;
    const int quad = lane >> 4;
    const int wr   = wave >> 1;          // wave row 0..1 (64 rows each)
    const int wc   = wave & 1;           // wave col 0..1 (48 cols each)
    const int row0 = blockIdx.y * TM;    // grid swapped: y = M blocks
    const int n0   = blockIdx.x * TN;    //               x = N blocks (fastest)

    const f32x4 zero = {0.f, 0.f, 0.f, 0.f};
    f32x4 acc[4][3];
    #pragma unroll
    for (int rt = 0; rt < 4; ++rt)
        #pragma unroll
        for (int ct = 0; ct < 3; ++ct) acc[rt][ct] = zero;

    // ---- staging geometry ----
    const int srow = lane >> 2;                                  // 0..15 (lds-direct path)
    const int scol = (((lane & 3) ^ ((lane >> 3) & 3))) * 8;     // inverse-swizzled src k-chunk
    const int ksw  = (quad ^ ((m16 >> 1) & 3)) * 8;              // swizzled read k-offset

    // reg-staged A geometry (f32 modes)
    const int srow_f = ((wave & 1) << 6) | lane;                 // 0..127
    const int khalf  = wave >> 1;                                // 0..1 (16 floats each)
    const float* A32  = (const float*)Apv;
    const ushort* A16 = (const ushort*)Apv;
    const float* arow  = A32 + (size_t)(row0 + srow_f) * K + khalf * 16;
    const float* arow2 = (AMODE == AM_F32ADD)
                         ? A2 + (size_t)(row0 + srow_f) * K + khalf * 16 : nullptr;

    float4 av0, av1, av2, av3;           // A in flight (16 floats)
    float4 bv0, bv1, bv2, bv3;           // second stream (ADD mode)

    auto issueA = [&](int k0) {
        av0 = *reinterpret_cast<const float4*>(arow + k0);
        av1 = *reinterpret_cast<const float4*>(arow + k0 + 4);
        av2 = *reinterpret_cast<const float4*>(arow + k0 + 8);
        av3 = *reinterpret_cast<const float4*>(arow + k0 + 12);
        if constexpr (AMODE == AM_F32ADD) {
            bv0 = *reinterpret_cast<const float4*>(arow2 + k0);
            bv1 = *reinterpret_cast<const float4*>(arow2 + k0 + 4);
            bv2 = *reinterpret_cast<const float4*>(arow2 + k0 + 8);
            bv3 = *reinterpret_cast<const float4*>(arow2 + k0 + 12);
        }
    };
    auto writeA = [&](int buf) {
        float4 v0 = av0, v1 = av1, v2 = av2, v3 = av3;
        if constexpr (AMODE == AM_F32ADD) {
            v0.x += bv0.x; v0.y += bv0.y; v0.z += bv0.z; v0.w += bv0.w;
            v1.x += bv1.x; v1.y += bv1.y; v1.z += bv1.z; v1.w += bv1.w;
            v2.x += bv2.x; v2.y += bv2.y; v2.z += bv2.z; v2.w += bv2.w;
            v3.x += bv3.x; v3.y += bv3.y; v3.z += bv3.z; v3.w += bv3.w;
        }
        const int r  = srow_f & 15;
        const int ck = srow_f >> 4;
        const int xr = (r >> 1) & 3;
        const int s0 = khalf * 2;
        u32x4 w0 = {pkbf(v0.x, v0.y), pkbf(v0.z, v0.w), pkbf(v1.x, v1.y), pkbf(v1.z, v1.w)};
        u32x4 w1 = {pkbf(v2.x, v2.y), pkbf(v2.z, v2.w), pkbf(v3.x, v3.y), pkbf(v3.z, v3.w)};
        *reinterpret_cast<u32x4*>(&Asb[buf][ck * 512 + r * 32 + ((s0 ^ xr) * 8)]) = w0;
        *reinterpret_cast<u32x4*>(&Asb[buf][ck * 512 + r * 32 + (((s0 + 1) ^ xr) * 8)]) = w1;
    };
    auto stageA_lds = [&](int buf, int k0) {   // AM_BF16 path
        #pragma unroll
        for (int c = 0; c < 2; ++c) {
            const int ch = wave + c * 4;
            async_cp16(A16 + (size_t)(row0 + ch * 16 + srow) * K + k0 + scol,
                       &Asb[buf][ch * 512 + lane * 8]);
        }
    };
    auto stageB = [&](int buf, int k0) {
        async_cp16(Bt + (size_t)(n0 + wave * 16 + srow) * K + k0 + scol,
                   &Bsb[buf][wave * 512 + lane * 8]);
        if (wave < 2)
            async_cp16(Bt + (size_t)(n0 + (wave + 4) * 16 + srow) * K + k0 + scol,
                       &Bsb[buf][(wave + 4) * 512 + lane * 8]);
    };

    // ---- prologue: stage tile 0 ----
    if constexpr (AMODE == AM_BF16) {
        stageA_lds(0, 0);
        stageB(0, 0);
    } else {
        issueA(0);
        stageB(0, 0);
        writeA(0);
    }
    __syncthreads();

    int cur = 0;
    for (int k0 = 0; k0 < K; k0 += BK) {
        const bool nx = (k0 + BK < K);
        if constexpr (AMODE == AM_BF16) {
            if (nx) { stageA_lds(cur ^ 1, k0 + BK); stageB(cur ^ 1, k0 + BK); }
        } else {
            if (nx) { issueA(k0 + BK); stageB(cur ^ 1, k0 + BK); }  // loads in flight
        }

        short8 afrag[4], bfrag[3];
        #pragma unroll
        for (int rt = 0; rt < 4; ++rt)
            afrag[rt] = *reinterpret_cast<const short8*>(
                &Asb[cur][(wr * 4 + rt) * 512 + m16 * 32 + ksw]);
        #pragma unroll
        for (int ct = 0; ct < 3; ++ct)
            bfrag[ct] = *reinterpret_cast<const short8*>(
                &Bsb[cur][(wc * 3 + ct) * 512 + m16 * 32 + ksw]);

        #pragma unroll
        for (int rt = 0; rt < 4; ++rt)
            #pragma unroll
            for (int ct = 0; ct < 3; ++ct)
                acc[rt][ct] = __builtin_amdgcn_mfma_f32_16x16x32_bf16(
                    afrag[rt], bfrag[ct], acc[rt][ct], 0, 0, 0);

        if constexpr (AMODE != AM_BF16) {
            if (nx) writeA(cur ^ 1);   // cvt+ds_write after MFMA covered the load latency
        }
        __syncthreads();
        cur ^= 1;
    }

    #pragma unroll
    for (int ct = 0; ct < 3; ++ct) {
        const int col = n0 + wc * 48 + ct * 16 + m16;
        const float bcol = bias[col];
        #pragma unroll
        for (int rt = 0; rt < 4; ++rt) {
            #pragma unroll
            for (int r = 0; r < 4; ++r) {
                const int row = row0 + wr * 64 + rt * 16 + quad * 4 + r;
                const float val = acc[rt][ct][r] + bcol;
                if constexpr (__is_same(OutT, float)) {
                    C[(size_t)row * ldc + col] = val;
                } else {
                    C[(size_t)row * ldc + col] = f2b(val);
                }
            }
        }
    }
}

// ---------------------------------------------------------------------------
// Deformable 3D trilinear attention — register/shuffle version, head-major.
__global__ void __launch_bounds__(256, 8)
deform_kernel(const ushort* __restrict__ vbuf,
              const float* __restrict__ mix,
              ushort* __restrict__ aout) {
    const int gl   = threadIdx.x >> 4;   // subgroup in block
    const int l    = threadIdx.x & 15;
    const int head = blockIdx.x / 640;                   // block-uniform
    const int bq   = (blockIdx.x % 640) * 16 + gl;       // b*NQ + q
    const int q    = bq % NQ;
    const int b    = bq / NQ;
    const int qx   = q % GW;
    const int qy   = q / GW;

    const float* mrow = mix + (size_t)bq * MIXW;

    // --- phase 1: softmax (lanes 0..11 hold one logit each) ---
    float lg = (l < NPTS) ? mrow[648 + head * NPTS + l] : -1e30f;
    float mx = lg;
    #pragma unroll
    for (int mk = 1; mk < 16; mk <<= 1) mx = fmaxf(mx, __shfl_xor(mx, mk, 16));
    float e = (l < NPTS) ? __expf(lg - mx) : 0.f;
    float s = e;
    #pragma unroll
    for (int mk = 1; mk < 16; mk <<= 1) s += __shfl_xor(s, mk, 16);

    // --- phase 1b: corner geometry for point l (lanes 0..11) ---
    float    cw[8];
    uint32_t coff[8];
    uint32_t mask = 0;
    {
        const float ap = e / s;
        const int pl = (l < NPTS) ? l : 0;
        const int ob = (head * NPTS + pl) * 3;
        const float ox = mrow[ob + 0];
        const float oy = mrow[ob + 1];
        const float oz = mrow[ob + 2];
        const float x = (float)qx + ox;          // = loc_x*W - 0.5
        const float y = (float)qy + oy;
        const float z = oz * (5.0f / 3.0f) - 0.5f;
        const float x0f = floorf(x), y0f = floorf(y), z0f = floorf(z);
        const int x0 = (int)x0f, y0 = (int)y0f, z0 = (int)z0f;
        const float fx = x - x0f, fy = y - y0f, fz = z - z0f;

        #pragma unroll
        for (int dz = 0; dz < 2; ++dz) {
            const int zi = z0 + dz;
            const bool zv = (zi >= 0) & (zi < DDEPTH);
            const int zc = min(max(zi, 0), DDEPTH - 1);
            const float wz = dz ? fz : 1.f - fz;
            #pragma unroll
            for (int dy = 0; dy < 2; ++dy) {
                const int yi = y0 + dy;
                const bool yv = (yi >= 0) & (yi < GH);
                const int yc = min(max(yi, 0), GH - 1);
                const float wy = dy ? fy : 1.f - fy;
                #pragma unroll
                for (int dx = 0; dx < 2; ++dx) {
                    const int xi = x0 + dx;
                    const bool xv = (xi >= 0) & (xi < GW);
                    const int xc = min(max(xi, 0), GW - 1);
                    const float wx = dx ? fx : 1.f - fx;
                    const int i = dz * 4 + dy * 2 + dx;
                    const bool valid = zv & yv & xv & (l < NPTS);
                    cw[i]   = ap * wz * wy * wx;
                    coff[i] = (uint32_t)((zc * GH + yc) * GW + xc) * (E_DIM / 2);
                    mask |= (valid ? (1u << i) : 0u);
                }
            }
        }
    }

    // --- phase 2: gather (all 16 lanes; lane = channel pair) ---
    const uint32_t* vb = reinterpret_cast<const uint32_t*>(vbuf)
                         + (size_t)b * NTOK * (E_DIM / 2) + head * (HDIM / 2) + l;
    float o0 = 0.f, o1 = 0.f;
    #pragma unroll
    for (int p = 0; p < NPTS; ++p) {
        const uint32_t msk = (uint32_t)__shfl((int)mask, p, 16);
        if (msk == 0) continue;   // near wave-uniform skip
        #pragma unroll
        for (int i = 0; i < 8; ++i) {
            if (msk & (1u << i)) {
                const float    w   = __shfl(cw[i], p, 16);
                const uint32_t off = (uint32_t)__shfl((int)coff[i], p, 16);
                const uint32_t pair = vb[off];
                o0 += w * b2f_lo(pair);
                o1 += w * b2f_hi(pair);
            }
        }
    }
    const uint32_t packed = (uint32_t)f2b(o0) | ((uint32_t)f2b(o1) << 16);
    reinterpret_cast<uint32_t*>(aout)[(size_t)bq * (E_DIM / 2) + head * (HDIM / 2) + l] = packed;
}

// ---------------------------------------------------------------------------
extern "C" void kernel_launch(void* const* d_in, const int* in_sizes, int n_in,
                              void* d_out, int out_size, void* d_ws, size_t ws_size,
                              hipStream_t stream) {
    const float* query     = (const float*)d_in[0];
    const float* value     = (const float*)d_in[1];
    const float* query_pos = (const float*)d_in[2];
    const float* W_off     = (const float*)d_in[3];
    const float* b_off     = (const float*)d_in[4];
    const float* W_attn    = (const float*)d_in[5];
    const float* b_attn    = (const float*)d_in[6];
    const float* W_v       = (const float*)d_in[7];
    const float* b_v       = (const float*)d_in[8];
    const float* W_out     = (const float*)d_in[9];
    const float* b_out     = (const float*)d_in[10];
    float* out = (float*)d_out;

    char* ws = (char*)d_ws;
    ushort* vbuf     = (ushort*)(ws);                  // 58,982,400
    ushort* aout     = (ushort*)(ws + 58982400);       // 11,796,480
    float*  mixb     = (float*) (ws + 70778880);       // 35,389,440
    ushort* wt_v     = (ushort*)(ws + 106168320);      // 663,552
    ushort* wt_out   = (ushort*)(ws + 106831872);      // 663,552
    ushort* wt_mix   = (ushort*)(ws + 107495424);      // 995,328
    float*  bias_mix = (float*) (ws + 108490752);      // 3,456

    prep_weights<<<(1161216 + 255) / 256, 256, 0, stream>>>(
        W_v, W_out, W_off, W_attn, b_off, b_attn, wt_v, wt_out, wt_mix, bias_mix);

    // mix = (query+query_pos) @ [W_off|W_attn] + bias : (10240 x 864), fp32 out
    // fused fp32 add+cast in A-staging
    gemm_mfma<AM_F32ADD, float><<<dim3(MIXW / TN, BQ_TOT / TM), 256, 0, stream>>>(
        query, query_pos, wt_mix, bias_mix, mixb, BQ_TOT, MIXW, E_DIM, MIXW);

    // v = value @ W_v + b_v : (51200 x 576), bf16 out — fused fp32 cast in A-staging
    gemm_mfma<AM_F32, ushort><<<dim3(E_DIM / TN, (BSZ * NTOK) / TM), 256, 0, stream>>>(
        value, nullptr, wt_v, b_v, vbuf, BSZ * NTOK, E_DIM, E_DIM, E_DIM);

    // deformable gather + softmax-weighted sum -> aout (bf16), head-major grid
    deform_kernel<<<HEADS * 640, 256, 0, stream>>>(vbuf, mixb, aout);

    // out = aout @ W_out + b_out : (10240 x 576), fp32 to d_out
    gemm_mfma<AM_BF16, float><<<dim3(E_DIM / TN, BQ_TOT / TM), 256, 0, stream>>>(
        aout, nullptr, wt_out, b_out, out, BQ_TOT, E_DIM, E_DIM, E_DIM);
}

// Round 4
// 396.123 us; speedup vs baseline: 1.2804x; 1.2804x over previous
//
#include <hip/hip_runtime.h>
#include <cstdint>

// Problem constants (fixed shapes)
#define E_DIM   576
#define HEADS   18
#define NPTS    12
#define DDEPTH  5
#define HDIM    32
#define BSZ     2
#define GH      64
#define GW      80
#define NQ      (GH*GW)       // 5120
#define NTOK    (NQ*DDEPTH)   // 25600
#define MIXW    864           // 648 offsets + 216 attn logits
#define BQ_TOT  (BSZ*NQ)      // 10240

typedef __attribute__((ext_vector_type(8))) short short8;
typedef __attribute__((ext_vector_type(4))) float f32x4;

__device__ __forceinline__ float b2f_lo(uint32_t u) {
    union { uint32_t u; float f; } v; v.u = u << 16; return v.f;
}
__device__ __forceinline__ float b2f_hi(uint32_t u) {
    union { uint32_t u; float f; } v; v.u = u & 0xffff0000u; return v.f;
}
__device__ __forceinline__ ushort f2b(float f) {
    union { float f; uint32_t u; } v; v.f = f;
    return (ushort)((v.u + 0x7fffu + ((v.u >> 16) & 1u)) >> 16);
}

// ---------------------------------------------------------------------------
// One fused prep kernel: value cast, (query+query_pos) cast, weight transposes,
// bias concat. Grid sized by the biggest range (value cast, 7.37M float4s);
// low-index threads additionally handle the smaller ranges.
__global__ void prep_all(const float* __restrict__ value,
                         const float* __restrict__ query, const float* __restrict__ query_pos,
                         const float* __restrict__ W_v, const float* __restrict__ W_out,
                         const float* __restrict__ W_off, const float* __restrict__ W_attn,
                         const float* __restrict__ b_off, const float* __restrict__ b_attn,
                         ushort* __restrict__ val_bf16, ushort* __restrict__ q_bf16,
                         ushort* __restrict__ wt_v, ushort* __restrict__ wt_out,
                         ushort* __restrict__ wt_mix, float* __restrict__ bias_mix) {
    const int i = blockIdx.x * blockDim.x + threadIdx.x;
    if (i < 51200 * 576 / 4) {
        const float4 v = reinterpret_cast<const float4*>(value)[i];
        ushort4 o; o.x = f2b(v.x); o.y = f2b(v.y); o.z = f2b(v.z); o.w = f2b(v.w);
        reinterpret_cast<ushort4*>(val_bf16)[i] = o;
    }
    if (i < 10240 * 576 / 4) {
        const float4 va = reinterpret_cast<const float4*>(query)[i];
        const float4 vb = reinterpret_cast<const float4*>(query_pos)[i];
        ushort4 o;
        o.x = f2b(va.x + vb.x); o.y = f2b(va.y + vb.y);
        o.z = f2b(va.z + vb.z); o.w = f2b(va.w + vb.w);
        reinterpret_cast<ushort4*>(q_bf16)[i] = o;
    }
    if (i < 864) bias_mix[i] = (i < 648) ? b_off[i] : b_attn[i - 648];
    if (i < 331776) {
        int n = i / E_DIM, k = i - n * E_DIM;
        wt_v[i] = f2b(W_v[(size_t)k * E_DIM + n]);
    } else if (i < 663552) {
        int j = i - 331776;
        int n = j / E_DIM, k = j - n * E_DIM;
        wt_out[j] = f2b(W_out[(size_t)k * E_DIM + n]);
    } else if (i < 1161216) {
        int j = i - 663552;
        int n = j / E_DIM, k = j - n * E_DIM;
        float v = (n < 648) ? W_off[(size_t)k * 648 + n] : W_attn[(size_t)k * 216 + (n - 648)];
        wt_mix[j] = f2b(v);
    }
}

// ---------------------------------------------------------------------------
// MFMA GEMM body: C[M,N] = A[M,K] @ Bt[N,K]^T + bias[N]   (A, Bt bf16)
// Tile 128x96, BK=32, 256 threads = 4 waves in a 2x2 grid (each wave 64x48).
// Round-1 proven structure: single-buffered, global_load_lds staging, XOR
// k-slot swizzle (phys_slot = logical ^ ((row>>1)&3)); inverse swizzle applied
// on the per-lane global source address (both-sides-or-neither).
// Verified: SQ_LDS_BANK_CONFLICT 5.53M -> 0; value GEMM ~68 us.
#define TM 128
#define TN 96
#define BK 32

__device__ __forceinline__ void async_cp16(const ushort* gsrc, ushort* ldst) {
    __builtin_amdgcn_global_load_lds(
        (const __attribute__((address_space(1))) void*)gsrc,
        (__attribute__((address_space(3))) void*)ldst, 16, 0, 0);
}

template <typename OutT>
__device__ __forceinline__ void gemm_body(ushort* __restrict__ smem, int bx, int by,
                                          const ushort* __restrict__ A,
                                          const ushort* __restrict__ Bt,
                                          const float* __restrict__ bias,
                                          OutT* __restrict__ C, int K, int ldc) {
    ushort* Asb = smem;              // TM*BK, 8 chunks of [16][32]
    ushort* Bsb = smem + TM * BK;    // TN*BK, 6 chunks of [16][32]
    const int tid  = threadIdx.x;
    const int wave = tid >> 6;
    const int lane = tid & 63;
    const int m16  = lane & 15;
    const int quad = lane >> 4;
    const int wr   = wave >> 1;          // wave row 0..1 (64 rows each)
    const int wc   = wave & 1;           // wave col 0..1 (48 cols each)
    const int row0 = bx * TM;
    const int n0   = by * TN;

    const f32x4 zero = {0.f, 0.f, 0.f, 0.f};
    f32x4 acc[4][3];
    #pragma unroll
    for (int rt = 0; rt < 4; ++rt)
        #pragma unroll
        for (int ct = 0; ct < 3; ++ct) acc[rt][ct] = zero;

    const int srow = lane >> 2;                                  // 0..15
    const int scol = (((lane & 3) ^ ((lane >> 3) & 3))) * 8;     // inverse-swizzled src k-chunk
    const int ksw  = (quad ^ ((m16 >> 1) & 3)) * 8;              // swizzled read k-offset

    for (int k0 = 0; k0 < K; k0 += BK) {
        #pragma unroll
        for (int c = 0; c < 2; ++c) {
            const int ch = wave + c * 4;
            async_cp16(A + (size_t)(row0 + ch * 16 + srow) * K + k0 + scol,
                       Asb + ch * 512 + lane * 8);
        }
        async_cp16(Bt + (size_t)(n0 + wave * 16 + srow) * K + k0 + scol,
                   Bsb + wave * 512 + lane * 8);
        if (wave < 2)
            async_cp16(Bt + (size_t)(n0 + (wave + 4) * 16 + srow) * K + k0 + scol,
                       Bsb + (wave + 4) * 512 + lane * 8);
        __syncthreads();

        short8 afrag[4], bfrag[3];
        #pragma unroll
        for (int rt = 0; rt < 4; ++rt)
            afrag[rt] = *reinterpret_cast<const short8*>(
                Asb + (wr * 4 + rt) * 512 + m16 * 32 + ksw);
        #pragma unroll
        for (int ct = 0; ct < 3; ++ct)
            bfrag[ct] = *reinterpret_cast<const short8*>(
                Bsb + (wc * 3 + ct) * 512 + m16 * 32 + ksw);

        #pragma unroll
        for (int rt = 0; rt < 4; ++rt)
            #pragma unroll
            for (int ct = 0; ct < 3; ++ct)
                acc[rt][ct] = __builtin_amdgcn_mfma_f32_16x16x32_bf16(
                    afrag[rt], bfrag[ct], acc[rt][ct], 0, 0, 0);

        __syncthreads();
    }

    #pragma unroll
    for (int ct = 0; ct < 3; ++ct) {
        const int col = n0 + wc * 48 + ct * 16 + m16;
        const float bcol = bias[col];
        #pragma unroll
        for (int rt = 0; rt < 4; ++rt) {
            #pragma unroll
            for (int r = 0; r < 4; ++r) {
                const int row = row0 + wr * 64 + rt * 16 + quad * 4 + r;
                const float val = acc[rt][ct][r] + bcol;
                if constexpr (__is_same(OutT, float)) {
                    C[(size_t)row * ldc + col] = val;
                } else {
                    C[(size_t)row * ldc + col] = f2b(val);
                }
            }
        }
    }
}

// standalone GEMM (out projection)
template <typename OutT>
__global__ void gemm_mfma(const ushort* __restrict__ A, const ushort* __restrict__ Bt,
                          const float* __restrict__ bias, OutT* __restrict__ C,
                          int K, int ldc) {
    __shared__ __align__(16) ushort smem[(TM + TN) * BK];
    gemm_body<OutT>(smem, blockIdx.x, blockIdx.y, A, Bt, bias, C, K, ldc);
}

// two independent GEMMs in one launch (mix: fp32 out; value: bf16 out).
// Blocks [0, split): GEMM1 with x=M fastest (bx = id % nbx1); rest: GEMM2.
__global__ void gemm_dual(const ushort* __restrict__ A1, const ushort* __restrict__ B1,
                          const float* __restrict__ bias1, float* __restrict__ C1,
                          int K1, int ldc1, int nbx1, int split,
                          const ushort* __restrict__ A2, const ushort* __restrict__ B2,
                          const float* __restrict__ bias2, ushort* __restrict__ C2,
                          int K2, int ldc2, int nbx2) {
    __shared__ __align__(16) ushort smem[(TM + TN) * BK];
    const int id = blockIdx.x;
    if (id < split) {
        gemm_body<float>(smem, id % nbx1, id / nbx1, A1, B1, bias1, C1, K1, ldc1);
    } else {
        const int j = id - split;
        gemm_body<ushort>(smem, j % nbx2, j / nbx2, A2, B2, bias2, C2, K2, ldc2);
    }
}

// ---------------------------------------------------------------------------
// Deformable 3D trilinear attention — LDS-staged corner data, head-major.
// 16 lanes per (b,q) group x block-uniform head. Phase 1: lane l<12 computes
// point l's softmax prob + 8 (weight, dword-offset) pairs + validity mask and
// stores them to LDS (13 KB/block). Phase 2: all 16 lanes loop points/corners,
// reading the pair with ONE subgroup-uniform ds_read_b64 (free broadcast)
// instead of 2 ds_bpermute per corner (~200 LDS-pipe ops/wave removed).
__global__ void __launch_bounds__(256, 8)
deform_kernel(const ushort* __restrict__ vbuf,
              const float* __restrict__ mix,
              ushort* __restrict__ aout) {
    __shared__ uint2 corn[16 * NPTS * 8];   // 12,288 B: [subgroup][point][corner]
    __shared__ uint32_t cmask[16 * NPTS];   // 768 B
    const int gl   = threadIdx.x >> 4;   // subgroup in block
    const int l    = threadIdx.x & 15;
    const int head = blockIdx.x / 640;                   // block-uniform
    const int bq   = (blockIdx.x % 640) * 16 + gl;       // b*NQ + q
    const int q    = bq % NQ;
    const int b    = bq / NQ;
    const int qx   = q % GW;
    const int qy   = q / GW;

    const float* mrow = mix + (size_t)bq * MIXW;

    // --- phase 1: softmax (lanes 0..11 hold one logit each) ---
    float lg = (l < NPTS) ? mrow[648 + head * NPTS + l] : -1e30f;
    float mx = lg;
    #pragma unroll
    for (int mk = 1; mk < 16; mk <<= 1) mx = fmaxf(mx, __shfl_xor(mx, mk, 16));
    float e = (l < NPTS) ? __expf(lg - mx) : 0.f;
    float s = e;
    #pragma unroll
    for (int mk = 1; mk < 16; mk <<= 1) s += __shfl_xor(s, mk, 16);

    // --- phase 1b: corner geometry for point l (lanes 0..11) ---
    float    cw[8];
    uint32_t coff[8];
    uint32_t mask = 0;
    {
        const float ap = e / s;
        const int pl = (l < NPTS) ? l : 0;
        const int ob = (head * NPTS + pl) * 3;
        const float ox = mrow[ob + 0];
        const float oy = mrow[ob + 1];
        const float oz = mrow[ob + 2];
        const float x = (float)qx + ox;          // = loc_x*W - 0.5
        const float y = (float)qy + oy;
        const float z = oz * (5.0f / 3.0f) - 0.5f;
        const float x0f = floorf(x), y0f = floorf(y), z0f = floorf(z);
        const int x0 = (int)x0f, y0 = (int)y0f, z0 = (int)z0f;
        const float fx = x - x0f, fy = y - y0f, fz = z - z0f;

        #pragma unroll
        for (int dz = 0; dz < 2; ++dz) {
            const int zi = z0 + dz;
            const bool zv = (zi >= 0) & (zi < DDEPTH);
            const int zc = min(max(zi, 0), DDEPTH - 1);
            const float wz = dz ? fz : 1.f - fz;
            #pragma unroll
            for (int dy = 0; dy < 2; ++dy) {
                const int yi = y0 + dy;
                const bool yv = (yi >= 0) & (yi < GH);
                const int yc = min(max(yi, 0), GH - 1);
                const float wy = dy ? fy : 1.f - fy;
                #pragma unroll
                for (int dx = 0; dx < 2; ++dx) {
                    const int xi = x0 + dx;
                    const bool xv = (xi >= 0) & (xi < GW);
                    const int xc = min(max(xi, 0), GW - 1);
                    const float wx = dx ? fx : 1.f - fx;
                    const int i = dz * 4 + dy * 2 + dx;
                    const bool valid = zv & yv & xv & (l < NPTS);
                    cw[i]   = ap * wz * wy * wx;
                    coff[i] = (uint32_t)((zc * GH + yc) * GW + xc) * (E_DIM / 2);
                    mask |= (valid ? (1u << i) : 0u);
                }
            }
        }
    }

    // --- stage corner data to LDS ---
    if (l < NPTS) {
        cmask[gl * NPTS + l] = mask;
        uint4* dst = reinterpret_cast<uint4*>(&corn[(gl * NPTS + l) * 8]);
        #pragma unroll
        for (int i2 = 0; i2 < 4; ++i2) {
            uint4 w;
            w.x = __float_as_uint(cw[2 * i2]);     w.y = coff[2 * i2];
            w.z = __float_as_uint(cw[2 * i2 + 1]); w.w = coff[2 * i2 + 1];
            dst[i2] = w;
        }
    }
    __syncthreads();

    // --- phase 2: gather (all 16 lanes; lane = channel pair) ---
    const uint32_t* vb = reinterpret_cast<const uint32_t*>(vbuf)
                         + (size_t)b * NTOK * (E_DIM / 2) + head * (HDIM / 2) + l;
    const uint2* cg = &corn[gl * NPTS * 8];
    float o0 = 0.f, o1 = 0.f;
    for (int p = 0; p < NPTS; ++p) {
        const uint32_t msk = cmask[gl * NPTS + p];
        if (msk == 0) continue;
        #pragma unroll
        for (int i = 0; i < 8; ++i) {
            if (msk & (1u << i)) {
                const uint2 wo = cg[p * 8 + i];        // uniform addr -> broadcast
                const float w = __uint_as_float(wo.x);
                const uint32_t pair = vb[wo.y];
                o0 += w * b2f_lo(pair);
                o1 += w * b2f_hi(pair);
            }
        }
    }
    const uint32_t packed = (uint32_t)f2b(o0) | ((uint32_t)f2b(o1) << 16);
    reinterpret_cast<uint32_t*>(aout)[(size_t)bq * (E_DIM / 2) + head * (HDIM / 2) + l] = packed;
}

// ---------------------------------------------------------------------------
extern "C" void kernel_launch(void* const* d_in, const int* in_sizes, int n_in,
                              void* d_out, int out_size, void* d_ws, size_t ws_size,
                              hipStream_t stream) {
    const float* query     = (const float*)d_in[0];
    const float* value     = (const float*)d_in[1];
    const float* query_pos = (const float*)d_in[2];
    const float* W_off     = (const float*)d_in[3];
    const float* b_off     = (const float*)d_in[4];
    const float* W_attn    = (const float*)d_in[5];
    const float* b_attn    = (const float*)d_in[6];
    const float* W_v       = (const float*)d_in[7];
    const float* b_v       = (const float*)d_in[8];
    const float* W_out     = (const float*)d_in[9];
    const float* b_out     = (const float*)d_in[10];
    float* out = (float*)d_out;

    char* ws = (char*)d_ws;
    ushort* vbuf     = (ushort*)(ws);                  // 58,982,400
    ushort* val_bf16 = (ushort*)(ws + 58982400);       // 58,982,400
    ushort* aout     = val_bf16;                       // alias (dead after value GEMM)
    ushort* q_bf16   = (ushort*)(ws + 117964800);      // 11,796,480
    float*  mixb     = (float*) (ws + 129761280);      // 35,389,440
    ushort* wt_v     = (ushort*)(ws + 165150720);      // 663,552
    ushort* wt_out   = (ushort*)(ws + 165814272);      // 663,552
    ushort* wt_mix   = (ushort*)(ws + 166477824);      // 995,328
    float*  bias_mix = (float*) (ws + 167473152);      // 3,456

    // fused prep: value cast + q cast-add + weight transposes + biases
    prep_all<<<(51200 * 576 / 4) / 256, 256, 0, stream>>>(
        value, query, query_pos, W_v, W_out, W_off, W_attn, b_off, b_attn,
        val_bf16, q_bf16, wt_v, wt_out, wt_mix, bias_mix);

    // mix GEMM (10240x864, fp32 out) + value GEMM (51200x576, bf16 out) in one launch
    // mix:   80 M-blocks x 9 N-blocks  = 720
    // value: 400 M-blocks x 6 N-blocks = 2400
    gemm_dual<<<720 + 2400, 256, 0, stream>>>(
        q_bf16, wt_mix, bias_mix, mixb, E_DIM, MIXW, BQ_TOT / TM, 720,
        val_bf16, wt_v, b_v, vbuf, E_DIM, E_DIM, (BSZ * NTOK) / TM);

    // deformable gather + softmax-weighted sum -> aout (bf16), head-major grid
    deform_kernel<<<HEADS * 640, 256, 0, stream>>>(vbuf, mixb, aout);

    // out = aout @ W_out + b_out : (10240 x 576), fp32 to d_out
    gemm_mfma<float><<<dim3(BQ_TOT / TM, E_DIM / TN), 256, 0, stream>>>(
        aout, wt_out, b_out, out, E_DIM, E_DIM);
}

// Round 5
// 357.495 us; speedup vs baseline: 1.4188x; 1.1081x over previous
//
#include <hip/hip_runtime.h>
#include <cstdint>

// Problem constants (fixed shapes)
#define E_DIM   576
#define HEADS   18
#define NPTS    12
#define DDEPTH  5
#define HDIM    32
#define BSZ     2
#define GH      64
#define GW      80
#define NQ      (GH*GW)       // 5120
#define NTOK    (NQ*DDEPTH)   // 25600
#define MIXW    864           // 648 offsets + 216 attn logits
#define BQ_TOT  (BSZ*NQ)      // 10240

typedef __attribute__((ext_vector_type(8))) short short8;
typedef __attribute__((ext_vector_type(4))) float f32x4;

__device__ __forceinline__ float b2f_lo(uint32_t u) {
    union { uint32_t u; float f; } v; v.u = u << 16; return v.f;
}
__device__ __forceinline__ float b2f_hi(uint32_t u) {
    union { uint32_t u; float f; } v; v.u = u & 0xffff0000u; return v.f;
}
__device__ __forceinline__ ushort f2b(float f) {
    union { float f; uint32_t u; } v; v.f = f;
    return (ushort)((v.u + 0x7fffu + ((v.u >> 16) & 1u)) >> 16);
}

// ---------------------------------------------------------------------------
// One fused prep kernel: value cast, (query+query_pos) cast, weight transposes,
// bias concat. HBM-bound at ~241 MB => ~40 us (at its floor).
__global__ void prep_all(const float* __restrict__ value,
                         const float* __restrict__ query, const float* __restrict__ query_pos,
                         const float* __restrict__ W_v, const float* __restrict__ W_out,
                         const float* __restrict__ W_off, const float* __restrict__ W_attn,
                         const float* __restrict__ b_off, const float* __restrict__ b_attn,
                         ushort* __restrict__ val_bf16, ushort* __restrict__ q_bf16,
                         ushort* __restrict__ wt_v, ushort* __restrict__ wt_out,
                         ushort* __restrict__ wt_mix, float* __restrict__ bias_mix) {
    const int i = blockIdx.x * blockDim.x + threadIdx.x;
    if (i < 51200 * 576 / 4) {
        const float4 v = reinterpret_cast<const float4*>(value)[i];
        ushort4 o; o.x = f2b(v.x); o.y = f2b(v.y); o.z = f2b(v.z); o.w = f2b(v.w);
        reinterpret_cast<ushort4*>(val_bf16)[i] = o;
    }
    if (i < 10240 * 576 / 4) {
        const float4 va = reinterpret_cast<const float4*>(query)[i];
        const float4 vb = reinterpret_cast<const float4*>(query_pos)[i];
        ushort4 o;
        o.x = f2b(va.x + vb.x); o.y = f2b(va.y + vb.y);
        o.z = f2b(va.z + vb.z); o.w = f2b(va.w + vb.w);
        reinterpret_cast<ushort4*>(q_bf16)[i] = o;
    }
    if (i < 864) bias_mix[i] = (i < 648) ? b_off[i] : b_attn[i - 648];
    if (i < 331776) {
        int n = i / E_DIM, k = i - n * E_DIM;
        wt_v[i] = f2b(W_v[(size_t)k * E_DIM + n]);
    } else if (i < 663552) {
        int j = i - 331776;
        int n = j / E_DIM, k = j - n * E_DIM;
        wt_out[j] = f2b(W_out[(size_t)k * E_DIM + n]);
    } else if (i < 1161216) {
        int j = i - 663552;
        int n = j / E_DIM, k = j - n * E_DIM;
        float v = (n < 648) ? W_off[(size_t)k * 648 + n] : W_attn[(size_t)k * 216 + (n - 648)];
        wt_mix[j] = f2b(v);
    }
}

// ---------------------------------------------------------------------------
// MFMA GEMM body: C[M,N] = A[M,K] @ Bt[N,K]^T + bias[N]   (A, Bt bf16)
// Tile 128x96, BK=32, 256 threads = 4 waves in a 2x2 grid (each wave 64x48).
// Round-1 proven structure: single-buffered, global_load_lds staging, XOR
// k-slot swizzle (phys_slot = logical ^ ((row>>1)&3)); inverse swizzle applied
// on the per-lane global source address. Verified: bank conflicts 5.53M -> 0.
//
// Block remap (new this round): XCD-chunked, N-fastest within chunk, so the
// nbn blocks sharing one A-panel are consecutive on ONE XCD -> A-panel is
// fetched from HBM once instead of nbn times (round-3 showed the sharers on
// different XCDs multiply HBM fetches; private L2s are not coherent/shared).
#define TM 128
#define TN 96
#define BK 32

__device__ __forceinline__ void async_cp16(const ushort* gsrc, ushort* ldst) {
    __builtin_amdgcn_global_load_lds(
        (const __attribute__((address_space(1))) void*)gsrc,
        (__attribute__((address_space(3))) void*)ldst, 16, 0, 0);
}

// id in [0, total), total % 8 == 0. Returns (bx=M-block, by=N-block).
__device__ __forceinline__ void xcd_map(int id, int total, int nbn, int& bx, int& by) {
    const int xcd = id & 7;
    const int pos = id >> 3;
    const int logical = xcd * (total >> 3) + pos;
    by = logical % nbn;
    bx = logical / nbn;
}

template <typename OutT>
__device__ __forceinline__ void gemm_body(ushort* __restrict__ smem, int bx, int by,
                                          const ushort* __restrict__ A,
                                          const ushort* __restrict__ Bt,
                                          const float* __restrict__ bias,
                                          OutT* __restrict__ C, int K, int ldc) {
    ushort* Asb = smem;              // TM*BK, 8 chunks of [16][32]
    ushort* Bsb = smem + TM * BK;    // TN*BK, 6 chunks of [16][32]
    const int tid  = threadIdx.x;
    const int wave = tid >> 6;
    const int lane = tid & 63;
    const int m16  = lane & 15;
    const int quad = lane >> 4;
    const int wr   = wave >> 1;          // wave row 0..1 (64 rows each)
    const int wc   = wave & 1;           // wave col 0..1 (48 cols each)
    const int row0 = bx * TM;
    const int n0   = by * TN;

    const f32x4 zero = {0.f, 0.f, 0.f, 0.f};
    f32x4 acc[4][3];
    #pragma unroll
    for (int rt = 0; rt < 4; ++rt)
        #pragma unroll
        for (int ct = 0; ct < 3; ++ct) acc[rt][ct] = zero;

    const int srow = lane >> 2;                                  // 0..15
    const int scol = (((lane & 3) ^ ((lane >> 3) & 3))) * 8;     // inverse-swizzled src k-chunk
    const int ksw  = (quad ^ ((m16 >> 1) & 3)) * 8;              // swizzled read k-offset

    for (int k0 = 0; k0 < K; k0 += BK) {
        #pragma unroll
        for (int c = 0; c < 2; ++c) {
            const int ch = wave + c * 4;
            async_cp16(A + (size_t)(row0 + ch * 16 + srow) * K + k0 + scol,
                       Asb + ch * 512 + lane * 8);
        }
        async_cp16(Bt + (size_t)(n0 + wave * 16 + srow) * K + k0 + scol,
                   Bsb + wave * 512 + lane * 8);
        if (wave < 2)
            async_cp16(Bt + (size_t)(n0 + (wave + 4) * 16 + srow) * K + k0 + scol,
                       Bsb + (wave + 4) * 512 + lane * 8);
        __syncthreads();

        short8 afrag[4], bfrag[3];
        #pragma unroll
        for (int rt = 0; rt < 4; ++rt)
            afrag[rt] = *reinterpret_cast<const short8*>(
                Asb + (wr * 4 + rt) * 512 + m16 * 32 + ksw);
        #pragma unroll
        for (int ct = 0; ct < 3; ++ct)
            bfrag[ct] = *reinterpret_cast<const short8*>(
                Bsb + (wc * 3 + ct) * 512 + m16 * 32 + ksw);

        #pragma unroll
        for (int rt = 0; rt < 4; ++rt)
            #pragma unroll
            for (int ct = 0; ct < 3; ++ct)
                acc[rt][ct] = __builtin_amdgcn_mfma_f32_16x16x32_bf16(
                    afrag[rt], bfrag[ct], acc[rt][ct], 0, 0, 0);

        __syncthreads();
    }

    #pragma unroll
    for (int ct = 0; ct < 3; ++ct) {
        const int col = n0 + wc * 48 + ct * 16 + m16;
        const float bcol = bias[col];
        #pragma unroll
        for (int rt = 0; rt < 4; ++rt) {
            #pragma unroll
            for (int r = 0; r < 4; ++r) {
                const int row = row0 + wr * 64 + rt * 16 + quad * 4 + r;
                const float val = acc[rt][ct][r] + bcol;
                if constexpr (__is_same(OutT, float)) {
                    C[(size_t)row * ldc + col] = val;
                } else {
                    C[(size_t)row * ldc + col] = f2b(val);
                }
            }
        }
    }
}

// standalone GEMM (out projection): 480 blocks = 80 M x 6 N, XCD-chunked
template <typename OutT>
__global__ void gemm_mfma(const ushort* __restrict__ A, const ushort* __restrict__ Bt,
                          const float* __restrict__ bias, OutT* __restrict__ C,
                          int K, int ldc, int total, int nbn) {
    __shared__ __align__(16) ushort smem[(TM + TN) * BK];
    int bx, by;
    xcd_map(blockIdx.x, total, nbn, bx, by);
    gemm_body<OutT>(smem, bx, by, A, Bt, bias, C, K, ldc);
}

// two independent GEMMs in one launch (mix: fp32 out; value: bf16 out).
__global__ void gemm_dual(const ushort* __restrict__ A1, const ushort* __restrict__ B1,
                          const float* __restrict__ bias1, float* __restrict__ C1,
                          int K1, int ldc1, int nbn1, int split,
                          const ushort* __restrict__ A2, const ushort* __restrict__ B2,
                          const float* __restrict__ bias2, ushort* __restrict__ C2,
                          int K2, int ldc2, int nbn2, int total2) {
    __shared__ __align__(16) ushort smem[(TM + TN) * BK];
    const int id = blockIdx.x;
    int bx, by;
    if (id < split) {
        xcd_map(id, split, nbn1, bx, by);
        gemm_body<float>(smem, bx, by, A1, B1, bias1, C1, K1, ldc1);
    } else {
        xcd_map(id - split, total2, nbn2, bx, by);
        gemm_body<ushort>(smem, bx, by, A2, B2, bias2, C2, K2, ldc2);
    }
}

// ---------------------------------------------------------------------------
// Deformable 3D trilinear attention — compacted-corner LDS version, head-major.
// 16 lanes per (b,q) subgroup x block-uniform head.
// Phase 1: lane l<12 computes point l's softmax prob + 8 corner (weight,
// dword-offset) pairs + validity; a 16-lane shfl prefix-sum compacts ONLY the
// valid pairs contiguously into LDS (order-preserving => bitwise-identical
// accumulation). Typical valid count ~31 of 96 (zero-init W_off => offsets =
// bias; most non-yaw points fall outside the depth range).
// Phase 2: branch-free uniform loop over the compacted list: one broadcast
// ds_read_b64 + one global_load_dword + 2 FMA per pair. No per-corner masks.
__global__ void __launch_bounds__(256, 8)
deform_kernel(const ushort* __restrict__ vbuf,
              const float* __restrict__ mix,
              ushort* __restrict__ aout) {
    __shared__ uint2 corn[16 * 97];      // 97-pair stride: subgroup bases on distinct banks
    __shared__ int   ccnt[16];
    const int gl   = threadIdx.x >> 4;   // subgroup in block
    const int l    = threadIdx.x & 15;
    const int head = blockIdx.x / 640;                   // block-uniform
    const int bq   = (blockIdx.x % 640) * 16 + gl;       // b*NQ + q
    const int q    = bq % NQ;
    const int b    = bq / NQ;
    const int qx   = q % GW;
    const int qy   = q / GW;

    const float* mrow = mix + (size_t)bq * MIXW;

    // --- phase 1: softmax (lanes 0..11 hold one logit each) ---
    float lg = (l < NPTS) ? mrow[648 + head * NPTS + l] : -1e30f;
    float mx = lg;
    #pragma unroll
    for (int mk = 1; mk < 16; mk <<= 1) mx = fmaxf(mx, __shfl_xor(mx, mk, 16));
    float e = (l < NPTS) ? __expf(lg - mx) : 0.f;
    float s = e;
    #pragma unroll
    for (int mk = 1; mk < 16; mk <<= 1) s += __shfl_xor(s, mk, 16);

    // --- phase 1b: corner geometry for point l (lanes 0..11) ---
    float    cw[8];
    uint32_t coff[8];
    uint32_t mask = 0;
    {
        const float ap = e / s;
        const int pl = (l < NPTS) ? l : 0;
        const int ob = (head * NPTS + pl) * 3;
        const float ox = mrow[ob + 0];
        const float oy = mrow[ob + 1];
        const float oz = mrow[ob + 2];
        const float x = (float)qx + ox;          // = loc_x*W - 0.5
        const float y = (float)qy + oy;
        const float z = oz * (5.0f / 3.0f) - 0.5f;
        const float x0f = floorf(x), y0f = floorf(y), z0f = floorf(z);
        const int x0 = (int)x0f, y0 = (int)y0f, z0 = (int)z0f;
        const float fx = x - x0f, fy = y - y0f, fz = z - z0f;

        #pragma unroll
        for (int dz = 0; dz < 2; ++dz) {
            const int zi = z0 + dz;
            const bool zv = (zi >= 0) & (zi < DDEPTH);
            const int zc = min(max(zi, 0), DDEPTH - 1);
            const float wz = dz ? fz : 1.f - fz;
            #pragma unroll
            for (int dy = 0; dy < 2; ++dy) {
                const int yi = y0 + dy;
                const bool yv = (yi >= 0) & (yi < GH);
                const int yc = min(max(yi, 0), GH - 1);
                const float wy = dy ? fy : 1.f - fy;
                #pragma unroll
                for (int dx = 0; dx < 2; ++dx) {
                    const int xi = x0 + dx;
                    const bool xv = (xi >= 0) & (xi < GW);
                    const int xc = min(max(xi, 0), GW - 1);
                    const float wx = dx ? fx : 1.f - fx;
                    const int i = dz * 4 + dy * 2 + dx;
                    const bool valid = zv & yv & xv & (l < NPTS);
                    cw[i]   = ap * wz * wy * wx;
                    coff[i] = (uint32_t)((zc * GH + yc) * GW + xc) * (E_DIM / 2);
                    mask |= (valid ? (1u << i) : 0u);
                }
            }
        }
    }

    // --- compaction: prefix-sum valid counts across the 16 lanes ---
    const int cnt = __popc(mask);
    int pre = cnt;                        // inclusive prefix
    #pragma unroll
    for (int mk = 1; mk < 16; mk <<= 1) {
        const int t = __shfl_up(pre, mk, 16);
        if (l >= mk) pre += t;
    }
    int o = gl * 97 + (pre - cnt);        // exclusive base for this point
    #pragma unroll
    for (int i = 0; i < 8; ++i) {
        if (mask & (1u << i)) {
            uint2 w; w.x = __float_as_uint(cw[i]); w.y = coff[i];
            corn[o] = w;
            ++o;
        }
    }
    if (l == 15) ccnt[gl] = pre;          // lane 15 inclusive = total valid
    __syncthreads();

    // --- phase 2: branch-free gather (all 16 lanes; lane = channel pair) ---
    const uint32_t lbase = (uint32_t)b * (uint32_t)(NTOK * (E_DIM / 2))
                         + (uint32_t)(head * (HDIM / 2) + l);
    const uint32_t* vb32 = reinterpret_cast<const uint32_t*>(vbuf);
    const int n = ccnt[gl];
    const uint2* cg = &corn[gl * 97];
    float o0 = 0.f, o1 = 0.f;
    #pragma unroll 2
    for (int j = 0; j < n; ++j) {
        const uint2 wo = cg[j];                 // uniform addr -> broadcast
        const uint32_t pair = vb32[lbase + wo.y];
        const float w = __uint_as_float(wo.x);
        o0 += w * b2f_lo(pair);
        o1 += w * b2f_hi(pair);
    }
    const uint32_t packed = (uint32_t)f2b(o0) | ((uint32_t)f2b(o1) << 16);
    reinterpret_cast<uint32_t*>(aout)[(size_t)bq * (E_DIM / 2) + head * (HDIM / 2) + l] = packed;
}

// ---------------------------------------------------------------------------
extern "C" void kernel_launch(void* const* d_in, const int* in_sizes, int n_in,
                              void* d_out, int out_size, void* d_ws, size_t ws_size,
                              hipStream_t stream) {
    const float* query     = (const float*)d_in[0];
    const float* value     = (const float*)d_in[1];
    const float* query_pos = (const float*)d_in[2];
    const float* W_off     = (const float*)d_in[3];
    const float* b_off     = (const float*)d_in[4];
    const float* W_attn    = (const float*)d_in[5];
    const float* b_attn    = (const float*)d_in[6];
    const float* W_v       = (const float*)d_in[7];
    const float* b_v       = (const float*)d_in[8];
    const float* W_out     = (const float*)d_in[9];
    const float* b_out     = (const float*)d_in[10];
    float* out = (float*)d_out;

    char* ws = (char*)d_ws;
    ushort* vbuf     = (ushort*)(ws);                  // 58,982,400
    ushort* val_bf16 = (ushort*)(ws + 58982400);       // 58,982,400
    ushort* aout     = val_bf16;                       // alias (dead after value GEMM)
    ushort* q_bf16   = (ushort*)(ws + 117964800);      // 11,796,480
    float*  mixb     = (float*) (ws + 129761280);      // 35,389,440
    ushort* wt_v     = (ushort*)(ws + 165150720);      // 663,552
    ushort* wt_out   = (ushort*)(ws + 165814272);      // 663,552
    ushort* wt_mix   = (ushort*)(ws + 166477824);      // 995,328
    float*  bias_mix = (float*) (ws + 167473152);      // 3,456

    // fused prep: value cast + q cast-add + weight transposes + biases
    prep_all<<<(51200 * 576 / 4) / 256, 256, 0, stream>>>(
        value, query, query_pos, W_v, W_out, W_off, W_attn, b_off, b_attn,
        val_bf16, q_bf16, wt_v, wt_out, wt_mix, bias_mix);

    // mix GEMM (10240x864, fp32 out, 80Mx9N=720) + value GEMM (51200x576,
    // bf16 out, 400Mx6N=2400) in one launch, both XCD-chunked N-fastest.
    gemm_dual<<<720 + 2400, 256, 0, stream>>>(
        q_bf16, wt_mix, bias_mix, mixb, E_DIM, MIXW, 9, 720,
        val_bf16, wt_v, b_v, vbuf, E_DIM, E_DIM, 6, 2400);

    // deformable gather + softmax-weighted sum -> aout (bf16), head-major grid
    deform_kernel<<<HEADS * 640, 256, 0, stream>>>(vbuf, mixb, aout);

    // out = aout @ W_out + b_out : (10240 x 576), fp32 to d_out
    gemm_mfma<float><<<480, 256, 0, stream>>>(
        aout, wt_out, b_out, out, E_DIM, E_DIM, 480, 6);
}